// Round 3
// baseline (196.510 us; speedup 1.0000x reference)
//
#include <hip/hip_runtime.h>

// GraphConv B=256,N=512,D=6,F=128,MAX_DEG=6.
// R2 post-mortem: 5 serialized launches cost ~100us; fused-gather GEMM was
// latency-bound (70KB LDS -> 2 blocks/CU, occupancy 15%). R3: 2 kernels.
//   K1: decode edges + degree + atomic scatter into per-degree id regions
//       (order within degree irrelevant) + fp32 gather-sum -> bf16 summed in ws
//       + W -> bf16 [d][n][k] transpose.
//   K2: per (degree,tile): W[d] in LDS (35KB total -> 4 blocks/CU), A-frags
//       loaded DIRECTLY from summed (global) in MFMA layout, 64 mfma/wave,
//       bias+relu, scattered stores.

typedef short bf16x8 __attribute__((ext_vector_type(8)));
typedef float f32x4  __attribute__((ext_vector_type(4)));
typedef unsigned short ushort_t;
typedef unsigned int uint_t;

constexpr int Nn = 512;
constexpr int Ff = 128;
constexpr int BN = 256 * 512;             // 131072 atoms

// ws layout (bytes)
constexpr size_t WS_GC     = 0;                         // i32 [6] (+pad to 256)
constexpr size_t WS_REGION = 256;                       // i32 [6][BN]
constexpr size_t WS_WT     = 256 + (size_t)6 * BN * 4;  // bf16 [6][128][128]
constexpr size_t WS_SUMMED = WS_WT + 196608;            // bf16 [BN][128]
constexpr size_t WS_NEEDED = WS_SUMMED + (size_t)BN * 128 * 2;   // ~36.9 MB

__device__ inline ushort_t f2bf(float f) {              // round-to-nearest-even
    uint_t u = __float_as_uint(f);
    return (ushort_t)((u + 0x7FFFu + ((u >> 16) & 1u)) >> 16);
}

__device__ inline bool detect_is64(const int* edges32) {
    // int64 edges: odd dwords are sign-extension words in {0,-1}.
    int probe = edges32[2 * (threadIdx.x & 63) + 1];
    return __any(probe > 0) == 0;
}

// ---------------- K1: decode + degree-scatter + gather-sum + Wt ----------------
__global__ __launch_bounds__(256, 3)
void k1_pre(const float* __restrict__ atoms,
            const int*   __restrict__ edges32,
            const float* __restrict__ W,
            int* __restrict__ gcnt,
            int* __restrict__ region,
            ushort_t* __restrict__ Wt,
            ushort_t* __restrict__ summed) {
    const int tid = threadIdx.x;
    const int blk = blockIdx.x;               // 1024 blocks x 128 atoms
    const int c0  = blk * 128;
    const bool is64 = detect_is64(edges32);

    __shared__ int eds_sh[128 * 6];
    __shared__ int wcnt[2][6];
    __shared__ int base_sh[6];

    // W -> bf16 transposed [d][n][k], spread over first 96 blocks (1024 elts ea)
    if (blk < 96) {
        #pragma unroll
        for (int i = 0; i < 4; i++) {
            int linear = blk * 1024 + i * 256 + tid;      // [d][k][n] linear
            int d = linear >> 14, rem = linear & 16383;
            int k = rem >> 7, n = rem & 127;
            Wt[d * 16384 + n * 128 + k] = f2bf(W[linear]);
        }
    }

    // phase 1: decode edges, degree, ballot ranks (threads 0..127, 2 full waves)
    int dg = 0, rank = 0;
    if (tid < 128) {
        const int a = c0 + tid;
        #pragma unroll
        for (int j = 0; j < 6; j++) {
            int e = is64 ? edges32[((size_t)a * 6 + j) * 2]
                         : edges32[(size_t)a * 6 + j];
            eds_sh[tid * 6 + j] = e;
            dg += (e != -1) ? 1 : 0;
        }
        const int lane = tid & 63, w = tid >> 6;
        unsigned long long bal[6];
        #pragma unroll
        for (int dv = 0; dv < 6; dv++) bal[dv] = __ballot(dg == dv);
        if (lane < 6) wcnt[w][lane] = (int)__popcll(bal[lane]);
        unsigned long long below = (lane == 0) ? 0ull : (bal[dg] << (64 - lane));
        rank = (int)__popcll(bal[dg] & ((lane == 63) ? 0x7FFFFFFFFFFFFFFFull
                                                     : ((1ull << lane) - 1ull)));
        (void)below;
    }
    __syncthreads();
    if (tid < 6) base_sh[tid] = atomicAdd(&gcnt[tid], wcnt[0][tid] + wcnt[1][tid]);
    __syncthreads();
    if (tid < 128) {
        int pos = base_sh[dg] + ((tid >> 6) ? wcnt[0][dg] : 0) + rank;
        region[dg * BN + pos] = c0 + tid;
    }

    // phase 2: gather-sum fp32 -> bf16 summed (2 threads/row)
    const int r = tid >> 1, h = tid & 1;
    const int a = c0 + r;
    const int molbase = c0 & ~(Nn - 1);
    const float4* self4 = (const float4*)(atoms + (size_t)a * Ff + h * 64);
    float4 acc[16];
    #pragma unroll
    for (int c = 0; c < 16; c++) acc[c] = self4[c];
    #pragma unroll
    for (int j = 0; j < 6; j++) {
        int e = eds_sh[r * 6 + j];
        if (e >= 0) {
            const float4* nb4 = (const float4*)(atoms + (size_t)(molbase + e) * Ff + h * 64);
            #pragma unroll
            for (int c = 0; c < 16; c++) {
                float4 v = nb4[c];
                acc[c].x += v.x; acc[c].y += v.y; acc[c].z += v.z; acc[c].w += v.w;
            }
        }
    }
    uint4* dst = (uint4*)(summed + (size_t)a * Ff + h * 64);
    #pragma unroll
    for (int c8 = 0; c8 < 8; c8++) {
        float4 p = acc[2 * c8], q = acc[2 * c8 + 1];
        uint4 o;
        o.x = (uint_t)f2bf(p.x) | ((uint_t)f2bf(p.y) << 16);
        o.y = (uint_t)f2bf(p.z) | ((uint_t)f2bf(p.w) << 16);
        o.z = (uint_t)f2bf(q.x) | ((uint_t)f2bf(q.y) << 16);
        o.w = (uint_t)f2bf(q.z) | ((uint_t)f2bf(q.w) << 16);
        dst[c8] = o;
    }
}

// ---------------- K2: GEMM (B in LDS, A-frags direct from global) ----------------
__global__ __launch_bounds__(256, 4)
void k2_gemm(const ushort_t* __restrict__ summed,
             const float*    __restrict__ bias,
             const ushort_t* __restrict__ Wt,
             const int*      __restrict__ region,
             const int*      __restrict__ gcnt,
             float*          __restrict__ out) {
    const int d = blockIdx.x;
    const int t = blockIdx.y;
    const int count = gcnt[d];
    const int m0 = t * 128;
    if (m0 >= count) return;
    const int nrows = min(128, count - m0);

    __shared__ __attribute__((aligned(16))) ushort_t Bsh[128 * 136];
    __shared__ int ids[128];

    const int tid = threadIdx.x;
    if (tid < 128) {
        int idx = m0 + tid;
        if (idx >= count) idx = count - 1;     // clamp; stores masked by nrows
        ids[tid] = region[d * BN + idx];
    }
    // stage B: Wt[d] bf16 [n][k] -> LDS pad 136
    {
        const uint4* Wg = (const uint4*)(Wt + (size_t)d * 16384);
        #pragma unroll
        for (int i = 0; i < 8; i++) {
            int idx = tid + i * 256;           // uint4 chunks, 2048 total
            int n = idx >> 4, c = idx & 15;
            *(uint4*)&Bsh[n * 136 + c * 8] = Wg[idx];
        }
    }
    __syncthreads();

    const int lane = tid & 63, w = tid >> 6;
    const int mrow = w * 32;
    const int kq = lane >> 4;                  // 0..3
    const int ml = lane & 15;

    // A-frags directly from global summed (MFMA A layout: m=ml, k=k0*32+kq*8..)
    bf16x8 af[2][4];
    #pragma unroll
    for (int mt = 0; mt < 2; mt++) {
        const int row = ids[mrow + mt * 16 + ml];
        const bf16x8* sp = (const bf16x8*)(summed + (size_t)row * Ff + kq * 8);
        #pragma unroll
        for (int k0 = 0; k0 < 4; k0++) af[mt][k0] = sp[k0 * 4];   // +32 elts
    }

    #pragma unroll
    for (int nt = 0; nt < 8; nt++) {
        bf16x8 bfr[4];
        #pragma unroll
        for (int k0 = 0; k0 < 4; k0++)
            bfr[k0] = *(const bf16x8*)&Bsh[(nt * 16 + ml) * 136 + k0 * 32 + kq * 8];
        f32x4 c0 = {0.f, 0.f, 0.f, 0.f}, c1 = {0.f, 0.f, 0.f, 0.f};
        #pragma unroll
        for (int k0 = 0; k0 < 4; k0++) {
            c0 = __builtin_amdgcn_mfma_f32_16x16x32_bf16(af[0][k0], bfr[k0], c0, 0, 0, 0);
            c1 = __builtin_amdgcn_mfma_f32_16x16x32_bf16(af[1][k0], bfr[k0], c1, 0, 0, 0);
        }
        const int col = nt * 16 + ml;
        const float bcol = bias[d * Ff + col];
        #pragma unroll
        for (int mt = 0; mt < 2; mt++) {
            f32x4 cc = mt ? c1 : c0;
            #pragma unroll
            for (int reg = 0; reg < 4; reg++) {
                int rl = mrow + mt * 16 + kq * 4 + reg;    // C/D: row=(lane>>4)*4+reg
                if (rl < nrows) {
                    float v = cc[reg] + bcol;
                    out[(size_t)ids[rl] * Ff + col] = v > 0.f ? v : 0.f;
                }
            }
        }
    }
}

// ---------------- fallback (round-1 kernel) if ws too small ----------------
__global__ __launch_bounds__(128, 2)
void graphconv_fallback(const float* __restrict__ atoms,
                        const int* __restrict__ edges_raw,
                        const float* __restrict__ W,
                        const float* __restrict__ bias,
                        float* __restrict__ out) {
    const int tid = threadIdx.x;
    const int d = blockIdx.x % 6;
    const int k = blockIdx.x / 6;
    const int a0 = k * 256;
    __shared__ int eds[256 * 6];
    __shared__ int list[256];
    __shared__ int cnt;
    __shared__ float sv[2][Ff];
    bool is64;
    { int v = edges_raw[2 * (tid & 63) + 1]; is64 = (__ballot(v > 0) == 0ull); }
    if (!is64) { for (int i = tid; i < 256 * 6; i += 128) eds[i] = edges_raw[a0 * 6 + i]; }
    else       { for (int i = tid; i < 256 * 6; i += 128) eds[i] = edges_raw[2 * (a0 * 6 + i)]; }
    if (tid == 0) cnt = 0;
    __syncthreads();
    for (int i = tid; i < 256; i += 128) {
        int deg = 0;
        #pragma unroll
        for (int j = 0; j < 6; j++) deg += (eds[i * 6 + j] != -1) ? 1 : 0;
        if (deg == d) { int p = atomicAdd(&cnt, 1); list[p] = i; }
    }
    float Wreg[Ff];
    { const float* Wd = W + (size_t)d * Ff * Ff;
      #pragma unroll
      for (int f = 0; f < Ff; f++) Wreg[f] = Wd[f * Ff + tid]; }
    const float breg = bias[d * Ff + tid];
    __syncthreads();
    const int n = cnt;
    const float* batch_atoms = atoms + (size_t)(a0 / Nn) * Nn * Ff;
    const int row0 = a0 % Nn;
    for (int ii = 0; ii < n; ii++) {
        const int i = list[ii];
        float s = batch_atoms[(row0 + i) * Ff + tid];
        #pragma unroll
        for (int j = 0; j < 6; j++) {
            int e = eds[i * 6 + j];
            if (e != -1) s += batch_atoms[e * Ff + tid];
        }
        float* buf = sv[ii & 1];
        buf[tid] = s;
        __syncthreads();
        float acc = breg;
        const float4* sv4 = (const float4*)buf;
        #pragma unroll
        for (int fc = 0; fc < Ff / 4; fc++) {
            float4 x = sv4[fc];
            acc = fmaf(x.x, Wreg[4 * fc + 0], acc);
            acc = fmaf(x.y, Wreg[4 * fc + 1], acc);
            acc = fmaf(x.z, Wreg[4 * fc + 2], acc);
            acc = fmaf(x.w, Wreg[4 * fc + 3], acc);
        }
        out[(size_t)(a0 + i) * Ff + tid] = fmaxf(acc, 0.0f);
    }
}

extern "C" void kernel_launch(void* const* d_in, const int* in_sizes, int n_in,
                              void* d_out, int out_size, void* d_ws, size_t ws_size,
                              hipStream_t stream) {
    const float* atoms = (const float*)d_in[0];
    const int*   edges = (const int*)d_in[1];
    const float* W     = (const float*)d_in[2];
    const float* bias  = (const float*)d_in[3];
    float*       outp  = (float*)d_out;

    if (ws_size >= WS_NEEDED) {
        char* ws = (char*)d_ws;
        int*      gcnt   = (int*)(ws + WS_GC);
        int*      region = (int*)(ws + WS_REGION);
        ushort_t* Wt     = (ushort_t*)(ws + WS_WT);
        ushort_t* summed = (ushort_t*)(ws + WS_SUMMED);

        hipMemsetAsync(gcnt, 0, 32, stream);
        k1_pre<<<1024, 256, 0, stream>>>(atoms, edges, W, gcnt, region, Wt, summed);
        k2_gemm<<<dim3(6, 1024), 256, 0, stream>>>(summed, bias, Wt, region, gcnt, outp);
    } else {
        graphconv_fallback<<<3072, 128, 0, stream>>>(atoms, edges, W, bias, outp);
    }
}

// Round 4
// 196.395 us; speedup vs baseline: 1.0006x; 1.0006x over previous
//
#include <hip/hip_runtime.h>

// GraphConv B=256,N=512,D=6,F=128,MAX_DEG=6.
// R3 post-mortem: k1 latency-bound (VALUBusy 6%, occ 31%, 1.55 TB/s fetch):
// 2 threads/row -> too few outstanding loads. R4:
//   K1: 8 threads/row (28 independent float4 loads/thread, 16-reg acc),
//       4096 blocks; half-wave does degree decode + ballot scatter.
//   K2: flat 1030-block grid mapped to (degree,tile) via gcnt prefix
//       (kills 5120 no-op dispatches); B in LDS (35KB -> 4 blk/CU),
//       A-frags direct from global summed in MFMA layout.

typedef short bf16x8 __attribute__((ext_vector_type(8)));
typedef float f32x4  __attribute__((ext_vector_type(4)));
typedef unsigned short ushort_t;
typedef unsigned int uint_t;

constexpr int Nn = 512;
constexpr int Ff = 128;
constexpr int BN = 256 * 512;             // 131072 atoms
constexpr int RPB = 32;                    // rows per k1 block
constexpr int K1B = BN / RPB;              // 4096 blocks

// ws layout (bytes)
constexpr size_t WS_GC     = 0;                         // i32 [6] (+pad to 256)
constexpr size_t WS_REGION = 256;                       // i32 [6][BN]
constexpr size_t WS_WT     = 256 + (size_t)6 * BN * 4;  // bf16 [6][128][128]
constexpr size_t WS_SUMMED = WS_WT + 196608;            // bf16 [BN][128]
constexpr size_t WS_NEEDED = WS_SUMMED + (size_t)BN * 128 * 2;   // ~36.9 MB

__device__ inline ushort_t f2bf(float f) {              // round-to-nearest-even
    uint_t u = __float_as_uint(f);
    return (ushort_t)((u + 0x7FFFu + ((u >> 16) & 1u)) >> 16);
}

__device__ inline bool detect_is64(const int* edges32) {
    // int64 edges: odd dwords are sign-extension words in {0,-1}.
    int probe = edges32[2 * (threadIdx.x & 63) + 1];
    return __any(probe > 0) == 0;
}

// ---------------- K1: decode + degree-scatter + gather-sum + Wt ----------------
__global__ __launch_bounds__(256, 4)
void k1_pre(const float* __restrict__ atoms,
            const int*   __restrict__ edges32,
            const float* __restrict__ W,
            int* __restrict__ gcnt,
            int* __restrict__ region,
            ushort_t* __restrict__ Wt,
            ushort_t* __restrict__ summed) {
    const int tid = threadIdx.x;
    const int blk = blockIdx.x;               // 4096 blocks x 32 rows
    const int c0  = blk * RPB;
    const bool is64 = detect_is64(edges32);   // convergent, all threads

    __shared__ int eds_sh[RPB * 6];

    // W -> bf16 transposed [d][n][k]: one element/thread over first 384 blocks
    if (blk < 384) {
        int linear = blk * 256 + tid;                 // [d][k][n] linear, 98304
        int d = linear >> 14, rem = linear & 16383;
        int k = rem >> 7, n = rem & 127;
        Wt[d * 16384 + n * 128 + k] = f2bf(W[linear]);
    }

    // phase A (half of wave 0): decode edges, degree, ballot-rank scatter
    if (tid < RPB) {
        const int a = c0 + tid;
        int dg = 0;
        #pragma unroll
        for (int j = 0; j < 6; j++) {
            int e = is64 ? edges32[((size_t)a * 6 + j) * 2]
                         : edges32[(size_t)a * 6 + j];
            eds_sh[tid * 6 + j] = e;
            dg += (e != -1) ? 1 : 0;
        }
        unsigned long long bal[6];
        #pragma unroll
        for (int dv = 0; dv < 6; dv++) bal[dv] = __ballot(dg == dv);
        int rank = (int)__popcll(bal[dg] & ((1ull << tid) - 1ull));
        int base = 0;
        if (tid < 6) base = atomicAdd(&gcnt[tid], (int)__popcll(bal[tid]));
        int mybase = __shfl(base, dg, 64);            // broadcast from lane dg
        region[dg * BN + mybase + rank] = a;
    }
    __syncthreads();

    // phase B: gather-sum, 8 threads/row, 16 floats (4 float4) each
    const int r = tid >> 3, h = tid & 7;
    const int a = c0 + r;
    const int molbase = c0 & ~(Nn - 1);
    const float4* self4 = (const float4*)(atoms + (size_t)a * Ff + h * 16);
    float4 acc[4];
    #pragma unroll
    for (int c = 0; c < 4; c++) acc[c] = self4[c];
    int e[6];
    #pragma unroll
    for (int j = 0; j < 6; j++) e[j] = eds_sh[r * 6 + j];
    #pragma unroll
    for (int j = 0; j < 6; j++) {
        if (e[j] >= 0) {
            const float4* nb4 = (const float4*)(atoms + (size_t)(molbase + e[j]) * Ff + h * 16);
            #pragma unroll
            for (int c = 0; c < 4; c++) {
                float4 v = nb4[c];
                acc[c].x += v.x; acc[c].y += v.y; acc[c].z += v.z; acc[c].w += v.w;
            }
        }
    }
    uint4 o0, o1;
    o0.x = (uint_t)f2bf(acc[0].x) | ((uint_t)f2bf(acc[0].y) << 16);
    o0.y = (uint_t)f2bf(acc[0].z) | ((uint_t)f2bf(acc[0].w) << 16);
    o0.z = (uint_t)f2bf(acc[1].x) | ((uint_t)f2bf(acc[1].y) << 16);
    o0.w = (uint_t)f2bf(acc[1].z) | ((uint_t)f2bf(acc[1].w) << 16);
    o1.x = (uint_t)f2bf(acc[2].x) | ((uint_t)f2bf(acc[2].y) << 16);
    o1.y = (uint_t)f2bf(acc[2].z) | ((uint_t)f2bf(acc[2].w) << 16);
    o1.z = (uint_t)f2bf(acc[3].x) | ((uint_t)f2bf(acc[3].y) << 16);
    o1.w = (uint_t)f2bf(acc[3].z) | ((uint_t)f2bf(acc[3].w) << 16);
    uint4* dst = (uint4*)(summed + (size_t)a * Ff + h * 16);
    dst[0] = o0;
    dst[1] = o1;
}

// ---------------- K2: GEMM (B in LDS, A-frags direct from global) ----------------
__global__ __launch_bounds__(256, 4)
void k2_gemm(const ushort_t* __restrict__ summed,
             const float*    __restrict__ bias,
             const ushort_t* __restrict__ Wt,
             const int*      __restrict__ region,
             const int*      __restrict__ gcnt,
             float*          __restrict__ out) {
    // map flat block id -> (degree d, tile t)
    int cnts[6];
    #pragma unroll
    for (int dd = 0; dd < 6; dd++) cnts[dd] = gcnt[dd];
    const int bid = blockIdx.x;
    int d = -1, t = 0, accum = 0;
    #pragma unroll
    for (int dd = 0; dd < 6; dd++) {
        int tl = (cnts[dd] + 127) >> 7;
        if (d < 0 && bid < accum + tl) { d = dd; t = bid - accum; }
        accum += tl;
    }
    if (d < 0) return;
    const int count = cnts[d];
    const int m0 = t * 128;
    const int nrows = min(128, count - m0);

    __shared__ __attribute__((aligned(16))) ushort_t Bsh[128 * 136];
    __shared__ int ids[128];

    const int tid = threadIdx.x;
    if (tid < 128) {
        int idx = m0 + tid;
        if (idx >= count) idx = count - 1;     // clamp; stores masked by nrows
        ids[tid] = region[d * BN + idx];
    }
    // stage B: Wt[d] bf16 [n][k] -> LDS pad 136
    {
        const uint4* Wg = (const uint4*)(Wt + (size_t)d * 16384);
        #pragma unroll
        for (int i = 0; i < 8; i++) {
            int idx = tid + i * 256;           // uint4 chunks, 2048 total
            int n = idx >> 4, c = idx & 15;
            *(uint4*)&Bsh[n * 136 + c * 8] = Wg[idx];
        }
    }
    __syncthreads();

    const int lane = tid & 63, w = tid >> 6;
    const int mrow = w * 32;
    const int kq = lane >> 4;                  // 0..3
    const int ml = lane & 15;

    // A-frags directly from global summed (MFMA A layout: m=ml, k=k0*32+kq*8..)
    bf16x8 af[2][4];
    #pragma unroll
    for (int mt = 0; mt < 2; mt++) {
        const int row = ids[mrow + mt * 16 + ml];
        const bf16x8* sp = (const bf16x8*)(summed + (size_t)row * Ff + kq * 8);
        #pragma unroll
        for (int k0 = 0; k0 < 4; k0++) af[mt][k0] = sp[k0 * 4];   // +32 elts
    }

    #pragma unroll
    for (int nt = 0; nt < 8; nt++) {
        bf16x8 bfr[4];
        #pragma unroll
        for (int k0 = 0; k0 < 4; k0++)
            bfr[k0] = *(const bf16x8*)&Bsh[(nt * 16 + ml) * 136 + k0 * 32 + kq * 8];
        f32x4 c0 = {0.f, 0.f, 0.f, 0.f}, c1 = {0.f, 0.f, 0.f, 0.f};
        #pragma unroll
        for (int k0 = 0; k0 < 4; k0++) {
            c0 = __builtin_amdgcn_mfma_f32_16x16x32_bf16(af[0][k0], bfr[k0], c0, 0, 0, 0);
            c1 = __builtin_amdgcn_mfma_f32_16x16x32_bf16(af[1][k0], bfr[k0], c1, 0, 0, 0);
        }
        const int col = nt * 16 + ml;
        const float bcol = bias[d * Ff + col];
        #pragma unroll
        for (int mt = 0; mt < 2; mt++) {
            f32x4 cc = mt ? c1 : c0;
            #pragma unroll
            for (int reg = 0; reg < 4; reg++) {
                int rl = mrow + mt * 16 + kq * 4 + reg;    // C/D: row=(lane>>4)*4+reg
                if (rl < nrows) {
                    float v = cc[reg] + bcol;
                    out[(size_t)ids[rl] * Ff + col] = v > 0.f ? v : 0.f;
                }
            }
        }
    }
}

// ---------------- fallback (round-1 kernel) if ws too small ----------------
__global__ __launch_bounds__(128, 2)
void graphconv_fallback(const float* __restrict__ atoms,
                        const int* __restrict__ edges_raw,
                        const float* __restrict__ W,
                        const float* __restrict__ bias,
                        float* __restrict__ out) {
    const int tid = threadIdx.x;
    const int d = blockIdx.x % 6;
    const int k = blockIdx.x / 6;
    const int a0 = k * 256;
    __shared__ int eds[256 * 6];
    __shared__ int list[256];
    __shared__ int cnt;
    __shared__ float sv[2][Ff];
    bool is64;
    { int v = edges_raw[2 * (tid & 63) + 1]; is64 = (__ballot(v > 0) == 0ull); }
    if (!is64) { for (int i = tid; i < 256 * 6; i += 128) eds[i] = edges_raw[a0 * 6 + i]; }
    else       { for (int i = tid; i < 256 * 6; i += 128) eds[i] = edges_raw[2 * (a0 * 6 + i)]; }
    if (tid == 0) cnt = 0;
    __syncthreads();
    for (int i = tid; i < 256; i += 128) {
        int deg = 0;
        #pragma unroll
        for (int j = 0; j < 6; j++) deg += (eds[i * 6 + j] != -1) ? 1 : 0;
        if (deg == d) { int p = atomicAdd(&cnt, 1); list[p] = i; }
    }
    float Wreg[Ff];
    { const float* Wd = W + (size_t)d * Ff * Ff;
      #pragma unroll
      for (int f = 0; f < Ff; f++) Wreg[f] = Wd[f * Ff + tid]; }
    const float breg = bias[d * Ff + tid];
    __syncthreads();
    const int n = cnt;
    const float* batch_atoms = atoms + (size_t)(a0 / Nn) * Nn * Ff;
    const int row0 = a0 % Nn;
    for (int ii = 0; ii < n; ii++) {
        const int i = list[ii];
        float s = batch_atoms[(row0 + i) * Ff + tid];
        #pragma unroll
        for (int j = 0; j < 6; j++) {
            int e = eds[i * 6 + j];
            if (e != -1) s += batch_atoms[e * Ff + tid];
        }
        float* buf = sv[ii & 1];
        buf[tid] = s;
        __syncthreads();
        float acc = breg;
        const float4* sv4 = (const float4*)buf;
        #pragma unroll
        for (int fc = 0; fc < Ff / 4; fc++) {
            float4 x = sv4[fc];
            acc = fmaf(x.x, Wreg[4 * fc + 0], acc);
            acc = fmaf(x.y, Wreg[4 * fc + 1], acc);
            acc = fmaf(x.z, Wreg[4 * fc + 2], acc);
            acc = fmaf(x.w, Wreg[4 * fc + 3], acc);
        }
        out[(size_t)(a0 + i) * Ff + tid] = fmaxf(acc, 0.0f);
    }
}

extern "C" void kernel_launch(void* const* d_in, const int* in_sizes, int n_in,
                              void* d_out, int out_size, void* d_ws, size_t ws_size,
                              hipStream_t stream) {
    const float* atoms = (const float*)d_in[0];
    const int*   edges = (const int*)d_in[1];
    const float* W     = (const float*)d_in[2];
    const float* bias  = (const float*)d_in[3];
    float*       outp  = (float*)d_out;

    if (ws_size >= WS_NEEDED) {
        char* ws = (char*)d_ws;
        int*      gcnt   = (int*)(ws + WS_GC);
        int*      region = (int*)(ws + WS_REGION);
        ushort_t* Wt     = (ushort_t*)(ws + WS_WT);
        ushort_t* summed = (ushort_t*)(ws + WS_SUMMED);

        hipMemsetAsync(gcnt, 0, 32, stream);
        k1_pre<<<K1B, 256, 0, stream>>>(atoms, edges, W, gcnt, region, Wt, summed);
        k2_gemm<<<1030, 256, 0, stream>>>(summed, bias, Wt, region, gcnt, outp);
    } else {
        graphconv_fallback<<<3072, 128, 0, stream>>>(atoms, edges, W, bias, outp);
    }
}

// Round 5
// 195.469 us; speedup vs baseline: 1.0053x; 1.0047x over previous
//
#include <hip/hip_runtime.h>

// GraphConv B=256,N=512,D=6,F=128,MAX_DEG=6.
// R4 post-mortem: k1 flat at 72us despite occ 31->76% -> not latency-bound.
// Culprit: address map. Old: thread(row,h) loads row*512 + h*64 + c*16 ->
// per instruction 64 lanes touch 64 distinct 64B lines (16B used each) =
// 64 TA requests/instr, ~29M total ~ 48us at 1 req/cy. R5: thread covers
// floats c*32+h*4 -> lanes 0-7 contiguous 128B -> 16 req/instr (4x fewer).

typedef short bf16x8 __attribute__((ext_vector_type(8)));
typedef float f32x4  __attribute__((ext_vector_type(4)));
typedef unsigned short ushort_t;
typedef unsigned int uint_t;

constexpr int Nn = 512;
constexpr int Ff = 128;
constexpr int BN = 256 * 512;             // 131072 atoms
constexpr int RPB = 32;                    // rows per k1 block
constexpr int K1B = BN / RPB;              // 4096 blocks

// ws layout (bytes)
constexpr size_t WS_GC     = 0;                         // i32 [6] (+pad to 256)
constexpr size_t WS_REGION = 256;                       // i32 [6][BN]
constexpr size_t WS_WT     = 256 + (size_t)6 * BN * 4;  // bf16 [6][128][128]
constexpr size_t WS_SUMMED = WS_WT + 196608;            // bf16 [BN][128]
constexpr size_t WS_NEEDED = WS_SUMMED + (size_t)BN * 128 * 2;   // ~36.9 MB

__device__ inline ushort_t f2bf(float f) {              // round-to-nearest-even
    uint_t u = __float_as_uint(f);
    return (ushort_t)((u + 0x7FFFu + ((u >> 16) & 1u)) >> 16);
}

__device__ inline bool detect_is64(const int* edges32) {
    // int64 edges: odd dwords are sign-extension words in {0,-1}.
    int probe = edges32[2 * (threadIdx.x & 63) + 1];
    return __any(probe > 0) == 0;
}

// ---------------- K1: decode + degree-scatter + gather-sum + Wt ----------------
__global__ __launch_bounds__(256, 4)
void k1_pre(const float* __restrict__ atoms,
            const int*   __restrict__ edges32,
            const float* __restrict__ W,
            int* __restrict__ gcnt,
            int* __restrict__ region,
            ushort_t* __restrict__ Wt,
            ushort_t* __restrict__ summed) {
    const int tid = threadIdx.x;
    const int blk = blockIdx.x;               // 4096 blocks x 32 rows
    const int c0  = blk * RPB;
    const bool is64 = detect_is64(edges32);   // convergent, all threads

    __shared__ int eds_sh[RPB * 6];

    // W -> bf16 transposed [d][n][k]: one element/thread over first 384 blocks
    if (blk < 384) {
        int linear = blk * 256 + tid;                 // [d][k][n] linear, 98304
        int d = linear >> 14, rem = linear & 16383;
        int k = rem >> 7, n = rem & 127;
        Wt[d * 16384 + n * 128 + k] = f2bf(W[linear]);
    }

    // phase A (half of wave 0): decode edges, degree, ballot-rank scatter
    if (tid < RPB) {
        const int a = c0 + tid;
        int dg = 0;
        #pragma unroll
        for (int j = 0; j < 6; j++) {
            int e = is64 ? edges32[((size_t)a * 6 + j) * 2]
                         : edges32[(size_t)a * 6 + j];
            eds_sh[tid * 6 + j] = e;
            dg += (e != -1) ? 1 : 0;
        }
        unsigned long long bal[6];
        #pragma unroll
        for (int dv = 0; dv < 6; dv++) bal[dv] = __ballot(dg == dv);
        int rank = (int)__popcll(bal[dg] & ((1ull << tid) - 1ull));
        int base = 0;
        if (tid < 6) base = atomicAdd(&gcnt[tid], (int)__popcll(bal[tid]));
        int mybase = __shfl(base, dg, 64);            // broadcast from lane dg
        region[dg * BN + mybase + rank] = a;
    }
    __syncthreads();

    // phase B: gather-sum, 8 threads/row. Thread (r,h) covers floats
    // c*32 + h*4 (c=0..3): lanes 0-7 load contiguous 128B per instruction.
    const int r = tid >> 3, h = tid & 7;
    const int a = c0 + r;
    const int molbase = c0 & ~(Nn - 1);
    const float4* self4 = (const float4*)(atoms + (size_t)a * Ff);
    float4 acc[4];
    #pragma unroll
    for (int c = 0; c < 4; c++) acc[c] = self4[c * 8 + h];
    int e[6];
    #pragma unroll
    for (int j = 0; j < 6; j++) e[j] = eds_sh[r * 6 + j];
    #pragma unroll
    for (int j = 0; j < 6; j++) {
        if (e[j] >= 0) {
            const float4* nb4 = (const float4*)(atoms + (size_t)(molbase + e[j]) * Ff);
            #pragma unroll
            for (int c = 0; c < 4; c++) {
                float4 v = nb4[c * 8 + h];
                acc[c].x += v.x; acc[c].y += v.y; acc[c].z += v.z; acc[c].w += v.w;
            }
        }
    }
    // store: thread's floats at byte offset c*64 + h*8 (uint2 = 4 bf16);
    // lanes 0-7 contiguous 64B per c.
    uint2* dstrow = (uint2*)(summed + (size_t)a * Ff);
    #pragma unroll
    for (int c = 0; c < 4; c++) {
        uint2 o;
        o.x = (uint_t)f2bf(acc[c].x) | ((uint_t)f2bf(acc[c].y) << 16);
        o.y = (uint_t)f2bf(acc[c].z) | ((uint_t)f2bf(acc[c].w) << 16);
        dstrow[c * 8 + h] = o;
    }
}

// ---------------- K2: GEMM (B in LDS, A-frags direct from global) ----------------
__global__ __launch_bounds__(256, 4)
void k2_gemm(const ushort_t* __restrict__ summed,
             const float*    __restrict__ bias,
             const ushort_t* __restrict__ Wt,
             const int*      __restrict__ region,
             const int*      __restrict__ gcnt,
             float*          __restrict__ out) {
    // map flat block id -> (degree d, tile t)
    int cnts[6];
    #pragma unroll
    for (int dd = 0; dd < 6; dd++) cnts[dd] = gcnt[dd];
    const int bid = blockIdx.x;
    int d = -1, t = 0, accum = 0;
    #pragma unroll
    for (int dd = 0; dd < 6; dd++) {
        int tl = (cnts[dd] + 127) >> 7;
        if (d < 0 && bid < accum + tl) { d = dd; t = bid - accum; }
        accum += tl;
    }
    if (d < 0) return;
    const int count = cnts[d];
    const int m0 = t * 128;
    const int nrows = min(128, count - m0);

    __shared__ __attribute__((aligned(16))) ushort_t Bsh[128 * 136];
    __shared__ int ids[128];

    const int tid = threadIdx.x;
    if (tid < 128) {
        int idx = m0 + tid;
        if (idx >= count) idx = count - 1;     // clamp; stores masked by nrows
        ids[tid] = region[d * BN + idx];
    }
    // stage B: Wt[d] bf16 [n][k] -> LDS pad 136
    {
        const uint4* Wg = (const uint4*)(Wt + (size_t)d * 16384);
        #pragma unroll
        for (int i = 0; i < 8; i++) {
            int idx = tid + i * 256;           // uint4 chunks, 2048 total
            int n = idx >> 4, c = idx & 15;
            *(uint4*)&Bsh[n * 136 + c * 8] = Wg[idx];
        }
    }
    __syncthreads();

    const int lane = tid & 63, w = tid >> 6;
    const int mrow = w * 32;
    const int kq = lane >> 4;                  // 0..3
    const int ml = lane & 15;

    // A-frags directly from global summed (MFMA A layout: m=ml, k=k0*32+kq*8..)
    bf16x8 af[2][4];
    #pragma unroll
    for (int mt = 0; mt < 2; mt++) {
        const int row = ids[mrow + mt * 16 + ml];
        const bf16x8* sp = (const bf16x8*)(summed + (size_t)row * Ff + kq * 8);
        #pragma unroll
        for (int k0 = 0; k0 < 4; k0++) af[mt][k0] = sp[k0 * 4];   // +32 elts
    }

    #pragma unroll
    for (int nt = 0; nt < 8; nt++) {
        bf16x8 bfr[4];
        #pragma unroll
        for (int k0 = 0; k0 < 4; k0++)
            bfr[k0] = *(const bf16x8*)&Bsh[(nt * 16 + ml) * 136 + k0 * 32 + kq * 8];
        f32x4 c0 = {0.f, 0.f, 0.f, 0.f}, c1 = {0.f, 0.f, 0.f, 0.f};
        #pragma unroll
        for (int k0 = 0; k0 < 4; k0++) {
            c0 = __builtin_amdgcn_mfma_f32_16x16x32_bf16(af[0][k0], bfr[k0], c0, 0, 0, 0);
            c1 = __builtin_amdgcn_mfma_f32_16x16x32_bf16(af[1][k0], bfr[k0], c1, 0, 0, 0);
        }
        const int col = nt * 16 + ml;
        const float bcol = bias[d * Ff + col];
        #pragma unroll
        for (int mt = 0; mt < 2; mt++) {
            f32x4 cc = mt ? c1 : c0;
            #pragma unroll
            for (int reg = 0; reg < 4; reg++) {
                int rl = mrow + mt * 16 + kq * 4 + reg;    // C/D: row=(lane>>4)*4+reg
                if (rl < nrows) {
                    float v = cc[reg] + bcol;
                    out[(size_t)ids[rl] * Ff + col] = v > 0.f ? v : 0.f;
                }
            }
        }
    }
}

// ---------------- fallback (round-1 kernel) if ws too small ----------------
__global__ __launch_bounds__(128, 2)
void graphconv_fallback(const float* __restrict__ atoms,
                        const int* __restrict__ edges_raw,
                        const float* __restrict__ W,
                        const float* __restrict__ bias,
                        float* __restrict__ out) {
    const int tid = threadIdx.x;
    const int d = blockIdx.x % 6;
    const int k = blockIdx.x / 6;
    const int a0 = k * 256;
    __shared__ int eds[256 * 6];
    __shared__ int list[256];
    __shared__ int cnt;
    __shared__ float sv[2][Ff];
    bool is64;
    { int v = edges_raw[2 * (tid & 63) + 1]; is64 = (__ballot(v > 0) == 0ull); }
    if (!is64) { for (int i = tid; i < 256 * 6; i += 128) eds[i] = edges_raw[a0 * 6 + i]; }
    else       { for (int i = tid; i < 256 * 6; i += 128) eds[i] = edges_raw[2 * (a0 * 6 + i)]; }
    if (tid == 0) cnt = 0;
    __syncthreads();
    for (int i = tid; i < 256; i += 128) {
        int deg = 0;
        #pragma unroll
        for (int j = 0; j < 6; j++) deg += (eds[i * 6 + j] != -1) ? 1 : 0;
        if (deg == d) { int p = atomicAdd(&cnt, 1); list[p] = i; }
    }
    float Wreg[Ff];
    { const float* Wd = W + (size_t)d * Ff * Ff;
      #pragma unroll
      for (int f = 0; f < Ff; f++) Wreg[f] = Wd[f * Ff + tid]; }
    const float breg = bias[d * Ff + tid];
    __syncthreads();
    const int n = cnt;
    const float* batch_atoms = atoms + (size_t)(a0 / Nn) * Nn * Ff;
    const int row0 = a0 % Nn;
    for (int ii = 0; ii < n; ii++) {
        const int i = list[ii];
        float s = batch_atoms[(row0 + i) * Ff + tid];
        #pragma unroll
        for (int j = 0; j < 6; j++) {
            int e = eds[i * 6 + j];
            if (e != -1) s += batch_atoms[e * Ff + tid];
        }
        float* buf = sv[ii & 1];
        buf[tid] = s;
        __syncthreads();
        float acc = breg;
        const float4* sv4 = (const float4*)buf;
        #pragma unroll
        for (int fc = 0; fc < Ff / 4; fc++) {
            float4 x = sv4[fc];
            acc = fmaf(x.x, Wreg[4 * fc + 0], acc);
            acc = fmaf(x.y, Wreg[4 * fc + 1], acc);
            acc = fmaf(x.z, Wreg[4 * fc + 2], acc);
            acc = fmaf(x.w, Wreg[4 * fc + 3], acc);
        }
        out[(size_t)(a0 + i) * Ff + tid] = fmaxf(acc, 0.0f);
    }
}

extern "C" void kernel_launch(void* const* d_in, const int* in_sizes, int n_in,
                              void* d_out, int out_size, void* d_ws, size_t ws_size,
                              hipStream_t stream) {
    const float* atoms = (const float*)d_in[0];
    const int*   edges = (const int*)d_in[1];
    const float* W     = (const float*)d_in[2];
    const float* bias  = (const float*)d_in[3];
    float*       outp  = (float*)d_out;

    if (ws_size >= WS_NEEDED) {
        char* ws = (char*)d_ws;
        int*      gcnt   = (int*)(ws + WS_GC);
        int*      region = (int*)(ws + WS_REGION);
        ushort_t* Wt     = (ushort_t*)(ws + WS_WT);
        ushort_t* summed = (ushort_t*)(ws + WS_SUMMED);

        hipMemsetAsync(gcnt, 0, 32, stream);
        k1_pre<<<K1B, 256, 0, stream>>>(atoms, edges, W, gcnt, region, Wt, summed);
        k2_gemm<<<1030, 256, 0, stream>>>(summed, bias, Wt, region, gcnt, outp);
    } else {
        graphconv_fallback<<<3072, 128, 0, stream>>>(atoms, edges, W, bias, outp);
    }
}

// Round 6
// 164.611 us; speedup vs baseline: 1.1938x; 1.1875x over previous
//
#include <hip/hip_runtime.h>

// GraphConv B=256,N=512,D=6,F=128,MAX_DEG=6.
// R5 post-mortem: k1 pinned at ~73us across 3 different gather structures
// (occupancy- and coalescing-invariant) -> limiter is the ~235MB random-row
// gather stream filling L2 from L3 (~3.2 TB/s). R6: eliminate cache gather.
// Block = (molecule, column-slice): stream 512x32-float slice + edges into
// LDS once (HBM reads each byte once, coalesced), gather neighbors from LDS
// (69 TB/s), write bf16 summed. Degree-scatter on slice-0 blocks via
// LDS-atomic ranks. k2 (MFMA GEMM) unchanged.

typedef short bf16x8 __attribute__((ext_vector_type(8)));
typedef float f32x4  __attribute__((ext_vector_type(4)));
typedef unsigned short ushort_t;
typedef unsigned int uint_t;

constexpr int Nn = 512;
constexpr int Ff = 128;
constexpr int BN = 256 * 512;             // 131072 atoms
constexpr int ROWSTRIDE = 34;             // LDS row pad: 32 floats + 2

// ws layout (bytes)
constexpr size_t WS_GC     = 0;                         // i32 [6] (+pad to 256)
constexpr size_t WS_REGION = 256;                       // i32 [6][BN]
constexpr size_t WS_WT     = 256 + (size_t)6 * BN * 4;  // bf16 [6][128][128]
constexpr size_t WS_SUMMED = WS_WT + 196608;            // bf16 [BN][128]
constexpr size_t WS_NEEDED = WS_SUMMED + (size_t)BN * 128 * 2;   // ~36.9 MB

__device__ inline ushort_t f2bf(float f) {              // round-to-nearest-even
    uint_t u = __float_as_uint(f);
    return (ushort_t)((u + 0x7FFFu + ((u >> 16) & 1u)) >> 16);
}

__device__ inline bool detect_is64(const int* edges32) {
    // int64 edges: odd dwords are sign-extension words in {0,-1}.
    int probe = edges32[2 * (threadIdx.x & 63) + 1];
    return __any(probe > 0) == 0;
}

// ---------------- K1: molecule-resident LDS gather ----------------
// grid: 1024 blocks = 256 molecules x 4 column-slices of 32 floats.
__global__ __launch_bounds__(256, 2)
void k1_pre(const float* __restrict__ atoms,
            const int*   __restrict__ edges32,
            const float* __restrict__ W,
            int* __restrict__ gcnt,
            int* __restrict__ region,
            ushort_t* __restrict__ Wt,
            ushort_t* __restrict__ summed) {
    const int tid   = threadIdx.x;
    const int mol   = blockIdx.x >> 2;
    const int slice = blockIdx.x & 3;
    const bool is64 = detect_is64(edges32);   // convergent

    __shared__ float    Arows[Nn * ROWSTRIDE];   // 69632 B
    __shared__ ushort_t nbp[Nn * 6];             // 6144 B (packed nbr ids)
    __shared__ int      hist[6], base_sh[6];

    // W -> bf16 transposed [d][n][k]: first 384 blocks, 256 elts each
    if (blockIdx.x < 384) {
        int linear = blockIdx.x * 256 + tid;          // [d][k][n] linear, 98304
        int d = linear >> 14, rem = linear & 16383;
        int k = rem >> 7, n = rem & 127;
        Wt[d * 16384 + n * 128 + k] = f2bf(W[linear]);
    }

    // ---- stage edges (packed u16; 0xFFFF = invalid) ----
    {
        const size_t ebase = (size_t)mol * (Nn * 6);
        for (int i = tid; i < Nn * 6; i += 256) {
            int e = is64 ? edges32[(ebase + i) * 2] : edges32[ebase + i];
            nbp[i] = (ushort_t)(e >= 0 ? e : 0xFFFF);
        }
    }

    // ---- stage atom slice: 512 rows x 32 floats, coalesced ----
    {
        const float4* gsrc = (const float4*)(atoms + (size_t)mol * (Nn * Ff) + slice * 32);
        #pragma unroll
        for (int it = 0; it < 16; it++) {
            int idx = tid + it * 256;         // float4 index in slice
            int row = idx >> 3, q = idx & 7;
            float4 v = gsrc[row * 32 + q];    // row stride 128 floats = 32 float4
            int la = row * ROWSTRIDE + q * 4;
            float2 p0; p0.x = v.x; p0.y = v.y;
            float2 p1; p1.x = v.z; p1.y = v.w;
            *(float2*)&Arows[la]     = p0;    // 8B-aligned (la even)
            *(float2*)&Arows[la + 2] = p1;
        }
    }
    __syncthreads();

    // ---- slice 0: degree-scatter via LDS-atomic ranks ----
    if (slice == 0) {
        if (tid < 6) hist[tid] = 0;
        __syncthreads();
        int dg[2], rk[2];
        #pragma unroll
        for (int s = 0; s < 2; s++) {
            int row = tid + s * 256;
            int dd = 0;
            #pragma unroll
            for (int j = 0; j < 6; j++) dd += (nbp[row * 6 + j] != 0xFFFF) ? 1 : 0;
            dg[s] = dd;
            rk[s] = atomicAdd(&hist[dd], 1);
        }
        __syncthreads();
        if (tid < 6) base_sh[tid] = atomicAdd(&gcnt[tid], hist[tid]);
        __syncthreads();
        #pragma unroll
        for (int s = 0; s < 2; s++)
            region[dg[s] * BN + base_sh[dg[s]] + rk[s]] = mol * Nn + tid + s * 256;
    }

    // ---- gather-sum from LDS: 4 threads/row x 8 floats, 8 rounds ----
    const int h = tid & 3, cbase = h * 8;
    #pragma unroll
    for (int rd = 0; rd < 8; rd++) {
        const int row = rd * 64 + (tid >> 2);
        float2 acc[4];
        #pragma unroll
        for (int c = 0; c < 4; c++)
            acc[c] = *(const float2*)&Arows[row * ROWSTRIDE + cbase + 2 * c];
        #pragma unroll
        for (int j = 0; j < 6; j++) {
            int e = nbp[row * 6 + j];
            if (e != 0xFFFF) {
                const float* src = &Arows[e * ROWSTRIDE + cbase];
                #pragma unroll
                for (int c = 0; c < 4; c++) {
                    float2 v = *(const float2*)&src[2 * c];
                    acc[c].x += v.x; acc[c].y += v.y;
                }
            }
        }
        uint4 o;
        o.x = (uint_t)f2bf(acc[0].x) | ((uint_t)f2bf(acc[0].y) << 16);
        o.y = (uint_t)f2bf(acc[1].x) | ((uint_t)f2bf(acc[1].y) << 16);
        o.z = (uint_t)f2bf(acc[2].x) | ((uint_t)f2bf(acc[2].y) << 16);
        o.w = (uint_t)f2bf(acc[3].x) | ((uint_t)f2bf(acc[3].y) << 16);
        *(uint4*)(summed + (size_t)(mol * Nn + row) * Ff + slice * 32 + cbase) = o;
    }
}

// ---------------- K2: GEMM (B in LDS, A-frags direct from global) ----------------
__global__ __launch_bounds__(256, 4)
void k2_gemm(const ushort_t* __restrict__ summed,
             const float*    __restrict__ bias,
             const ushort_t* __restrict__ Wt,
             const int*      __restrict__ region,
             const int*      __restrict__ gcnt,
             float*          __restrict__ out) {
    // map flat block id -> (degree d, tile t)
    int cnts[6];
    #pragma unroll
    for (int dd = 0; dd < 6; dd++) cnts[dd] = gcnt[dd];
    const int bid = blockIdx.x;
    int d = -1, t = 0, accum = 0;
    #pragma unroll
    for (int dd = 0; dd < 6; dd++) {
        int tl = (cnts[dd] + 127) >> 7;
        if (d < 0 && bid < accum + tl) { d = dd; t = bid - accum; }
        accum += tl;
    }
    if (d < 0) return;
    const int count = cnts[d];
    const int m0 = t * 128;
    const int nrows = min(128, count - m0);

    __shared__ __attribute__((aligned(16))) ushort_t Bsh[128 * 136];
    __shared__ int ids[128];

    const int tid = threadIdx.x;
    if (tid < 128) {
        int idx = m0 + tid;
        if (idx >= count) idx = count - 1;     // clamp; stores masked by nrows
        ids[tid] = region[d * BN + idx];
    }
    // stage B: Wt[d] bf16 [n][k] -> LDS pad 136
    {
        const uint4* Wg = (const uint4*)(Wt + (size_t)d * 16384);
        #pragma unroll
        for (int i = 0; i < 8; i++) {
            int idx = tid + i * 256;           // uint4 chunks, 2048 total
            int n = idx >> 4, c = idx & 15;
            *(uint4*)&Bsh[n * 136 + c * 8] = Wg[idx];
        }
    }
    __syncthreads();

    const int lane = tid & 63, w = tid >> 6;
    const int mrow = w * 32;
    const int kq = lane >> 4;                  // 0..3
    const int ml = lane & 15;

    // A-frags directly from global summed (MFMA A layout: m=ml, k=k0*32+kq*8..)
    bf16x8 af[2][4];
    #pragma unroll
    for (int mt = 0; mt < 2; mt++) {
        const int row = ids[mrow + mt * 16 + ml];
        const bf16x8* sp = (const bf16x8*)(summed + (size_t)row * Ff + kq * 8);
        #pragma unroll
        for (int k0 = 0; k0 < 4; k0++) af[mt][k0] = sp[k0 * 4];   // +32 elts
    }

    #pragma unroll
    for (int nt = 0; nt < 8; nt++) {
        bf16x8 bfr[4];
        #pragma unroll
        for (int k0 = 0; k0 < 4; k0++)
            bfr[k0] = *(const bf16x8*)&Bsh[(nt * 16 + ml) * 136 + k0 * 32 + kq * 8];
        f32x4 c0 = {0.f, 0.f, 0.f, 0.f}, c1 = {0.f, 0.f, 0.f, 0.f};
        #pragma unroll
        for (int k0 = 0; k0 < 4; k0++) {
            c0 = __builtin_amdgcn_mfma_f32_16x16x32_bf16(af[0][k0], bfr[k0], c0, 0, 0, 0);
            c1 = __builtin_amdgcn_mfma_f32_16x16x32_bf16(af[1][k0], bfr[k0], c1, 0, 0, 0);
        }
        const int col = nt * 16 + ml;
        const float bcol = bias[d * Ff + col];
        #pragma unroll
        for (int mt = 0; mt < 2; mt++) {
            f32x4 cc = mt ? c1 : c0;
            #pragma unroll
            for (int reg = 0; reg < 4; reg++) {
                int rl = mrow + mt * 16 + kq * 4 + reg;    // C/D: row=(lane>>4)*4+reg
                if (rl < nrows) {
                    float v = cc[reg] + bcol;
                    out[(size_t)ids[rl] * Ff + col] = v > 0.f ? v : 0.f;
                }
            }
        }
    }
}

// ---------------- fallback (round-1 kernel) if ws too small ----------------
__global__ __launch_bounds__(128, 2)
void graphconv_fallback(const float* __restrict__ atoms,
                        const int* __restrict__ edges_raw,
                        const float* __restrict__ W,
                        const float* __restrict__ bias,
                        float* __restrict__ out) {
    const int tid = threadIdx.x;
    const int d = blockIdx.x % 6;
    const int k = blockIdx.x / 6;
    const int a0 = k * 256;
    __shared__ int eds[256 * 6];
    __shared__ int list[256];
    __shared__ int cnt;
    __shared__ float sv[2][Ff];
    bool is64;
    { int v = edges_raw[2 * (tid & 63) + 1]; is64 = (__ballot(v > 0) == 0ull); }
    if (!is64) { for (int i = tid; i < 256 * 6; i += 128) eds[i] = edges_raw[a0 * 6 + i]; }
    else       { for (int i = tid; i < 256 * 6; i += 128) eds[i] = edges_raw[2 * (a0 * 6 + i)]; }
    if (tid == 0) cnt = 0;
    __syncthreads();
    for (int i = tid; i < 256; i += 128) {
        int deg = 0;
        #pragma unroll
        for (int j = 0; j < 6; j++) deg += (eds[i * 6 + j] != -1) ? 1 : 0;
        if (deg == d) { int p = atomicAdd(&cnt, 1); list[p] = i; }
    }
    float Wreg[Ff];
    { const float* Wd = W + (size_t)d * Ff * Ff;
      #pragma unroll
      for (int f = 0; f < Ff; f++) Wreg[f] = Wd[f * Ff + tid]; }
    const float breg = bias[d * Ff + tid];
    __syncthreads();
    const int n = cnt;
    const float* batch_atoms = atoms + (size_t)(a0 / Nn) * Nn * Ff;
    const int row0 = a0 % Nn;
    for (int ii = 0; ii < n; ii++) {
        const int i = list[ii];
        float s = batch_atoms[(row0 + i) * Ff + tid];
        #pragma unroll
        for (int j = 0; j < 6; j++) {
            int e = eds[i * 6 + j];
            if (e != -1) s += batch_atoms[e * Ff + tid];
        }
        float* buf = sv[ii & 1];
        buf[tid] = s;
        __syncthreads();
        float acc = breg;
        const float4* sv4 = (const float4*)buf;
        #pragma unroll
        for (int fc = 0; fc < Ff / 4; fc++) {
            float4 x = sv4[fc];
            acc = fmaf(x.x, Wreg[4 * fc + 0], acc);
            acc = fmaf(x.y, Wreg[4 * fc + 1], acc);
            acc = fmaf(x.z, Wreg[4 * fc + 2], acc);
            acc = fmaf(x.w, Wreg[4 * fc + 3], acc);
        }
        out[(size_t)(a0 + i) * Ff + tid] = fmaxf(acc, 0.0f);
    }
}

extern "C" void kernel_launch(void* const* d_in, const int* in_sizes, int n_in,
                              void* d_out, int out_size, void* d_ws, size_t ws_size,
                              hipStream_t stream) {
    const float* atoms = (const float*)d_in[0];
    const int*   edges = (const int*)d_in[1];
    const float* W     = (const float*)d_in[2];
    const float* bias  = (const float*)d_in[3];
    float*       outp  = (float*)d_out;

    if (ws_size >= WS_NEEDED) {
        char* ws = (char*)d_ws;
        int*      gcnt   = (int*)(ws + WS_GC);
        int*      region = (int*)(ws + WS_REGION);
        ushort_t* Wt     = (ushort_t*)(ws + WS_WT);
        ushort_t* summed = (ushort_t*)(ws + WS_SUMMED);

        hipMemsetAsync(gcnt, 0, 32, stream);
        k1_pre<<<1024, 256, 0, stream>>>(atoms, edges, W, gcnt, region, Wt, summed);
        k2_gemm<<<1030, 256, 0, stream>>>(summed, bias, Wt, region, gcnt, outp);
    } else {
        graphconv_fallback<<<3072, 128, 0, stream>>>(atoms, edges, W, bias, outp);
    }
}